// Round 7
// baseline (100.776 us; speedup 1.0000x reference)
//
#include <hip/hip_runtime.h>
#include <hip/hip_bf16.h>
#include <math.h>

#define N 2048
#define NC 8

// ws layout:
//   [0, 64)              : double acc[8]          (zeroed by k_prep block 0)
//   [64, 64+128K)        : float2 pack[8][2048]   {s/ln2, A/ln2} packed by k_prep
//   [64+128K, 64+192K)   : int    lohi[8][2048]   (lo | hi<<16, per ORIGINAL row)
//   [64+192K, +4)        : unsigned counter       (ticket for fused finalize)

#if __has_builtin(__builtin_amdgcn_exp2f)
__device__ __forceinline__ float fexp2(float x) { return __builtin_amdgcn_exp2f(x); }
#else
__device__ __forceinline__ float fexp2(float x) { return exp2f(x); }
#endif
#if __has_builtin(__builtin_amdgcn_logf)
__device__ __forceinline__ float flog2(float x) { return __builtin_amdgcn_logf(x); }
#else
__device__ __forceinline__ float flog2(float x) { return log2f(x); }
#endif

#define INV_LN2 1.4426950408889634f
#define LN2_D   0.6931471805599453
#define CLAMP2  (-144.26950408889634f)   /* -100/ln2 : clamp in log2 domain */

// ---------------- Kernel 1: fused A-sum + counting-rank GT + packing ----------
// R6 EXPERIMENT (resubmitted after infra failure; one variable, continuing
// R5's validated occupancy lever): grid 1024 -> 2048 blocks. R5 (2->4
// blocks/CU) gained 3.9us; k_prep is latency-bound. To reach 8 blocks/CU the
// two halves' LDS is UNIONED (asum: s+part = 10KB; sortgt: keys+pr+pv = 18KB;
// union 18KB -> 8 blocks/CU vs 28KB separate -> 5). Geometry: 16 j's/block,
// 16 i-slices of 128. Numerically a pure REGROUPING of f64 sums / integer
// ranks (R4/R5: absmax 0.0).
// blocks [0,1024):    A[j] = sum_i |s_j - s_i| ; pack[col][j] = {s,A}/ln2
// blocks [1024,2048): counting-rank windows -> lohi
__global__ __launch_bounds__(256) void k_prep(const float* __restrict__ logits,
                                              const float* __restrict__ dur,
                                              const int* __restrict__ ev,
                                              float2* __restrict__ pack,
                                              int* __restrict__ lohi,
                                              double* __restrict__ acc,
                                              unsigned* __restrict__ counter) {
    __shared__ union {
        struct { float s[N]; double part[256]; } a;                       // 10 KB
        struct { unsigned long long keys[N]; int pr[256]; int pv[256]; } g; // 18 KB
    } u;

    int b = blockIdx.x;
    int tid = threadIdx.x;

    if (b == 0) {  // zero accumulators + ticket for k_bce (stream-ordered)
        if (tid < 8) acc[tid] = 0.0;
        else if (tid == 8) counter[0] = 0u;
    }

    if (b < 1024) {
        // ---- A-sum, 16 j's per block, 16 i-slices of 128 (f64: exactness) ----
        int col = b >> 7, chunk = b & 127;
        for (int k = 0; k < N / 256; ++k) {
            int i = tid + k * 256;
            u.a.s[i] = logits[i * NC + col];
        }
        __syncthreads();
        int jl = tid & 15, slice = tid >> 4;   // 16 j-lanes x 16 slices
        int j = chunk * 16 + jl;
        float sj = u.a.s[j];
        int base = slice * 128;
        double a0 = 0.0, a1 = 0.0, a2 = 0.0, a3 = 0.0;
        #pragma unroll 2
        for (int i = 0; i < 128; i += 4) {
            a0 += (double)fabsf(sj - u.a.s[base + i]);
            a1 += (double)fabsf(sj - u.a.s[base + i + 1]);
            a2 += (double)fabsf(sj - u.a.s[base + i + 2]);
            a3 += (double)fabsf(sj - u.a.s[base + i + 3]);
        }
        u.a.part[tid] = (a0 + a1) + (a2 + a3);
        __syncthreads();
        if (tid < 16) {
            double v = 0.0;
            #pragma unroll
            for (int w = 0; w < 16; ++w) v += u.a.part[tid + (w << 4)];
            pack[col * N + j] = make_float2(sj * INV_LN2, (float)v * INV_LN2);
        }
    } else {
        // ---- counting-rank GT windows, 16 j's per block, 16 slices of 128 ----
        // key = (dur_bits<<32)|(i<<1)|e : ascending u64 == stable ascending by d
        int b2 = b - 1024;
        int col = b2 >> 7, chunk = b2 & 127;
        for (int k = 0; k < N / 256; ++k) {
            int i = tid + k * 256;
            unsigned int db = __float_as_uint(dur[i * NC + col]);  // dur in [0,1)
            int e = ev[i * NC + col];
            u.g.keys[i] = ((unsigned long long)db << 32) | (unsigned int)((i << 1) | e);
        }
        __syncthreads();
        int jl = tid & 15, slice = tid >> 4;
        int j = chunk * 16 + jl;
        unsigned long long kj = u.g.keys[j];
        int base = slice * 128;
        int rank = 0, evlt = 0;
        #pragma unroll 4
        for (int i = 0; i < 128; ++i) {
            unsigned long long ki = u.g.keys[base + i];
            int lt = (ki < kj) ? 1 : 0;
            rank += lt;
            evlt += lt & (int)(ki & 1ull);
        }
        u.g.pr[tid] = rank;
        u.g.pv[tid] = evlt;
        __syncthreads();
        if (tid < 16) {
            int r = 0, v = 0;
            #pragma unroll
            for (int w = 0; w < 16; ++w) {
                r += u.g.pr[tid + (w << 4)];
                v += u.g.pv[tid + (w << 4)];
            }
            int e = (int)(kj & 1ull);
            int hi = e ? (r + 1) : N;
            lohi[col * N + j] = v | (hi << 16);
        }
    }
}

// ---------------- Kernel 2: softmax+BCE — BYTE-IDENTICAL to measured r12 ------
// (98.43 us total; one-variable discipline: only k_prep changed this round.)
__global__ __launch_bounds__(256) void k_bce(const float2* __restrict__ pack,
                                             const int* __restrict__ lohi,
                                             double* __restrict__ acc,
                                             unsigned* __restrict__ counter,
                                             float* __restrict__ out) {
    int col = blockIdx.x >> 7;   // 0..7
    int rg  = blockIdx.x & 127;  // 0..127 (16 rows each)
    __shared__ float4 sa4[N / 2];   // 16 KB, LIVE through all passes
    __shared__ double bsum[4];      // block reduction buffer
    int tid = threadIdx.x;
    int wave = tid >> 6, lane = tid & 63;

    const float4* p4 = (const float4*)(pack + (size_t)col * N);
    #pragma unroll
    for (int k = 0; k < 4; ++k) {
        int i = tid + (k << 8);
        sa4[i] = p4[i];
    }
    __syncthreads();

    int row0 = (rg << 4) + (wave << 2);
    float sc0 = (float)(N - 1 - 2 * row0);

    int lh[4];
    #pragma unroll
    for (int c = 0; c < 4; ++c) lh[c] = lohi[col * N + row0 + c];

    // pass 1: max of row 0 ONLY (m0 frame)
    float m = -INFINITY;
    #pragma unroll
    for (int k = 0; k < 16; ++k) {
        float4 q = sa4[lane + (k << 6)];
        float t0 = fmaf(sc0, q.x, -q.y);
        float t1 = fmaf(sc0, q.z, -q.w);
        m = fmaxf(m, fmaxf(t0, t1));
    }
    #pragma unroll
    for (int off = 32; off > 0; off >>= 1)
        m = fmaxf(m, __shfl_xor(m, off, 64));

    // pass 2: se_c = sum_j 2^(t_c - m0); rows 1..3 by incremental multiply
    float se0 = 0.0f, se1 = 0.0f, se2 = 0.0f, se3 = 0.0f;
    #pragma unroll
    for (int k = 0; k < 16; ++k) {
        float4 q = sa4[lane + (k << 6)];
        {
            float g = fexp2(-(q.x + q.x));
            float E = fexp2(fmaf(sc0, q.x, -q.y) - m);
            se0 += E; E *= g;
            se1 += E; E *= g;
            se2 += E; E *= g;
            se3 += E;
        }
        {
            float g = fexp2(-(q.z + q.z));
            float E = fexp2(fmaf(sc0, q.z, -q.w) - m);
            se0 += E; E *= g;
            se1 += E; E *= g;
            se2 += E; E *= g;
            se3 += E;
        }
    }
    #pragma unroll
    for (int off = 32; off > 0; off >>= 1) {
        se0 += __shfl_xor(se0, off, 64);
        se1 += __shfl_xor(se1, off, 64);
        se2 += __shfl_xor(se2, off, 64);
        se3 += __shfl_xor(se3, off, 64);
    }
    float se[4] = {se0, se1, se2, se3};

    float C2v[4], yv[4];
    unsigned lo[4], wl[4];
    double rbase = 0.0;
    #pragma unroll
    for (int c = 0; c < 4; ++c) {
        float L2 = flog2(se[c]);
        rbase -= 2048.0 * (double)L2;
        C2v[c] = CLAMP2 + L2;
        lo[c] = (unsigned)(lh[c] & 0xffff);
        wl[c] = (unsigned)((lh[c] >> 16) & 0xffff) - lo[c];
        yv[c] = 1.0f / (float)wl[c];
    }

    // pass 3: a1_c = sum max(log2(se_c - E_c), C2_c); a2_c = windowed (mx1-mx2)
    float a1[4] = {0.0f, 0.0f, 0.0f, 0.0f};
    float a2[4] = {0.0f, 0.0f, 0.0f, 0.0f};
    #pragma unroll
    for (int k = 0; k < 16; ++k) {
        float4 q = sa4[lane + (k << 6)];
        int j0 = (lane + (k << 6)) << 1;
        {
            float tsv = q.x + q.x;
            float g = fexp2(-tsv);
            float x = fmaf(sc0, q.x, -q.y) - m;
            float E = fexp2(x);
            #pragma unroll
            for (int c = 0; c < 4; ++c) {
                float mx2 = fmaxf(flog2(se[c] - E), C2v[c]);
                a1[c] += mx2;
                float mx1 = fmaxf(x, C2v[c]);
                float w = ((unsigned)(j0 - lo[c]) < wl[c]) ? (mx1 - mx2) : 0.0f;
                a2[c] += w;
                E *= g;
                x -= tsv;
            }
        }
        {
            float tsv = q.z + q.z;
            float g = fexp2(-tsv);
            float x = fmaf(sc0, q.z, -q.w) - m;
            float E = fexp2(x);
            #pragma unroll
            for (int c = 0; c < 4; ++c) {
                float mx2 = fmaxf(flog2(se[c] - E), C2v[c]);
                a1[c] += mx2;
                float mx1 = fmaxf(x, C2v[c]);
                float w = ((unsigned)(j0 + 1 - lo[c]) < wl[c]) ? (mx1 - mx2) : 0.0f;
                a2[c] += w;
                E *= g;
                x -= tsv;
            }
        }
    }
    float r = 0.0f;
    #pragma unroll
    for (int c = 0; c < 4; ++c) r += fmaf(yv[c], a2[c], a1[c]);
    #pragma unroll
    for (int off = 32; off > 0; off >>= 1)
        r += __shfl_xor(r, off, 64);

    if (lane == 0) bsum[wave] = rbase + (double)r;
    __syncthreads();
    if (tid == 0) {
        double tot = (bsum[0] + bsum[1]) + (bsum[2] + bsum[3]);
        atomicAdd(&acc[col], LN2_D * tot);
        __threadfence();
        unsigned old = atomicAdd(counter, 1u);
        if (old == (unsigned)(NC * 128 - 1)) {  // last of 1024 blocks
            __threadfence();
            float ssum = 0.0f;
            int cnt = 0;
            for (int c = 0; c < NC; ++c) {
                double av2 = atomicAdd(&acc[c], 0.0);  // device-scope read
                float lc = (float)(-av2 / ((double)N * (double)N));
                if (lc > 0.0f) { ssum += lc; cnt++; }
            }
            out[0] = ssum / (float)(cnt > 0 ? cnt : 1);
        }
    }
}

extern "C" void kernel_launch(void* const* d_in, const int* in_sizes, int n_in,
                              void* d_out, int out_size, void* d_ws, size_t ws_size,
                              hipStream_t stream) {
    const float* logits    = (const float*)d_in[0];
    const int*   events    = (const int*)d_in[1];
    const float* durations = (const float*)d_in[2];
    float* out = (float*)d_out;

    char* ws = (char*)d_ws;
    double*   acc     = (double*)ws;
    float2*   pack    = (float2*)(ws + 64);
    int*      lohi    = (int*)(ws + 64 + (size_t)NC * N * sizeof(float2));
    unsigned* counter = (unsigned*)(ws + 64 + (size_t)NC * N * (sizeof(float2) + sizeof(int)));

    k_prep<<<dim3(2048), 256, 0, stream>>>(logits, durations, events, pack, lohi, acc, counter);
    k_bce<<<dim3(NC * 128), 256, 0, stream>>>(pack, lohi, acc, counter, out);
}